// Round 15
// baseline (450.851 us; speedup 1.0000x reference)
//
#include <hip/hip_runtime.h>
#include <cstdint>
#include <cstddef>

// ---------------------------------------------------------------------------
// CADGroupingGNN: 3x GCNConv(128->128) + MLP classifier, N=50000, E=800000.
// Round 15: GEMM software pipeline. The tile loop was stage->barrier->compute
// serialized (VALUBusy 18%, 69us vs 10.4us FMA floor). Now each iteration
// issues the NEXT tile's global loads into registers, computes the current
// tile from LDS (hides load latency), then regs->LDS after the barrier.
// Agg stays at the proven round-6 form (69us chip-wide gather service floor).
// fp32 mandatory (bf16/fp16 flip saturated sigmoids, snorm~1e4 amplify).
// ---------------------------------------------------------------------------

// ---- exclusive scan of cnt[] over N elements (3 kernels) ----
__global__ __launch_bounds__(256) void k_scan1(
    const int* __restrict__ cnt, int* __restrict__ start,
    int* __restrict__ bsum, int n) {
  __shared__ int s[256];
  int t = threadIdx.x, idx = blockIdx.x * 256 + t;
  s[t] = (idx < n) ? cnt[idx] : 0;
  for (int d = 1; d < 256; d <<= 1) {
    __syncthreads();
    int x = (t >= d) ? s[t - d] : 0;
    __syncthreads();
    s[t] += x;
  }
  __syncthreads();
  if (idx < n) start[idx + 1] = s[t];          // inclusive, per-block
  if (t == 255) bsum[blockIdx.x] = s[255];
}

__global__ __launch_bounds__(256) void k_scan2(int* __restrict__ bsum, int nb) {
  __shared__ int s[256];
  int t = threadIdx.x;
  s[t] = (t < nb) ? bsum[t] : 0;
  for (int d = 1; d < 256; d <<= 1) {
    __syncthreads();
    int x = (t >= d) ? s[t - d] : 0;
    __syncthreads();
    s[t] += x;
  }
  __syncthreads();
  if (t < nb) bsum[t] = s[t];                  // inclusive block sums
}

__global__ __launch_bounds__(256) void k_scan3(
    int* __restrict__ start, const int* __restrict__ bsum, int n) {
  int b = blockIdx.x, idx = b * 256 + threadIdx.x;
  if (idx < n) {
    int off = (b > 0) ? bsum[b - 1] : 0;
    start[idx + 1] += off;
    if (idx == 0) start[0] = 0;
  }
}

// atomic-free bucket fill: p = start[col] + rank; writes src index + raw ew
__global__ __launch_bounds__(256) void k_fill(
    const int* __restrict__ attr, const float* __restrict__ emb,
    const int* __restrict__ row, const int* __restrict__ col,
    const int* __restrict__ rank, const int* __restrict__ start,
    int* __restrict__ srcs, float* __restrict__ ew_s, int E) {
  int e = blockIdx.x * 256 + threadIdx.x;
  if (e < E) {
    int p = start[col[e]] + rank[e];
    srcs[p] = row[e];
    ew_s[p] = emb[attr[e]];
  }
}

// per-node deterministic degree sum (raw ew in wts) -> dinv, snorm
__global__ __launch_bounds__(256) void k_deg_csr(
    const int* __restrict__ start, const float* __restrict__ ew_s,
    float* __restrict__ dinv, float* __restrict__ snorm, int n) {
  int i = blockIdx.x * 256 + threadIdx.x;
  if (i >= n) return;
  int s = start[i], e = start[i + 1];
  float d = 1.0f;                              // self-loop weight
  for (int p = s; p < e; ++p) d += ew_s[p];
  float v = d > 0.f ? rsqrtf(d) : 0.f;
  dinv[i] = v;
  snorm[i] = v * v;
}

// edge-parallel weight normalization: wts[p] = dinv[row]*emb*dinv[col]
__global__ __launch_bounds__(256) void k_wts_edge(
    const int* __restrict__ attr, const float* __restrict__ emb,
    const int* __restrict__ row, const int* __restrict__ col,
    const int* __restrict__ rank, const int* __restrict__ start,
    const float* __restrict__ dinv, float* __restrict__ wts, int E) {
  int e = blockIdx.x * 256 + threadIdx.x;
  if (e < E) {
    int c = col[e];
    int p = start[c] + rank[e];
    wts[p] = dinv[row[e]] * emb[attr[e]] * dinv[c];
  }
}

__device__ __forceinline__ void agg_fma(float s, const float4& v, float4& acc) {
  acc.x = fmaf(s, v.x, acc.x);
  acc.y = fmaf(s, v.y, acc.y);
  acc.z = fmaf(s, v.z, acc.z);
  acc.w = fmaf(s, v.w, acc.w);
}

// out[i][:] = bias + snorm[i]*h[i][:] + sum_e wts[e]*h[srcs[e]][:]
// 32 lanes per node, float4 per lane (128 channels). 8-deep gather pipeline.
__global__ __launch_bounds__(256) void k_agg_csr(
    const float* __restrict__ h, const int* __restrict__ start,
    const int* __restrict__ srcs, const float* __restrict__ wts,
    const float* __restrict__ snorm, const float* __restrict__ bias,
    float* __restrict__ out, int n) {
  int tid = blockIdx.x * 256 + threadIdx.x;
  int i = tid >> 5;
  if (i >= n) return;
  int lane = tid & 31;
  const float4* h4 = (const float4*)h;
  float4 acc = ((const float4*)bias)[lane];
  float sn = snorm[i];
  float4 hv = h4[(size_t)i * 32 + lane];
  agg_fma(sn, hv, acc);

  int e = start[i], eend = start[i + 1];

  while (e < eend && (e & 3)) {
    float w = wts[e];
    float4 v = h4[(size_t)srcs[e] * 32 + lane];
    agg_fma(w, v, acc);
    ++e;
  }

  for (; e + 8 <= eend; e += 8) {
    int4   s0 = *(const int4*)&srcs[e];
    int4   s1 = *(const int4*)&srcs[e + 4];
    float4 w0 = *(const float4*)&wts[e];
    float4 w1 = *(const float4*)&wts[e + 4];
    float4 v0 = h4[(size_t)s0.x * 32 + lane];
    float4 v1 = h4[(size_t)s0.y * 32 + lane];
    float4 v2 = h4[(size_t)s0.z * 32 + lane];
    float4 v3 = h4[(size_t)s0.w * 32 + lane];
    float4 v4 = h4[(size_t)s1.x * 32 + lane];
    float4 v5 = h4[(size_t)s1.y * 32 + lane];
    float4 v6 = h4[(size_t)s1.z * 32 + lane];
    float4 v7 = h4[(size_t)s1.w * 32 + lane];
    agg_fma(w0.x, v0, acc); agg_fma(w0.y, v1, acc);
    agg_fma(w0.z, v2, acc); agg_fma(w0.w, v3, acc);
    agg_fma(w1.x, v4, acc); agg_fma(w1.y, v5, acc);
    agg_fma(w1.z, v6, acc); agg_fma(w1.w, v7, acc);
  }

  if (e + 4 <= eend) {
    int4   s0 = *(const int4*)&srcs[e];
    float4 w0 = *(const float4*)&wts[e];
    float4 v0 = h4[(size_t)s0.x * 32 + lane];
    float4 v1 = h4[(size_t)s0.y * 32 + lane];
    float4 v2 = h4[(size_t)s0.z * 32 + lane];
    float4 v3 = h4[(size_t)s0.w * 32 + lane];
    agg_fma(w0.x, v0, acc); agg_fma(w0.y, v1, acc);
    agg_fma(w0.z, v2, acc); agg_fma(w0.w, v3, acc);
    e += 4;
  }

  for (; e < eend; ++e) {
    float w = wts[e];
    float4 v = h4[(size_t)srcs[e] * 32 + lane];
    agg_fma(w, v, acc);
  }

  ((float4*)out)[(size_t)i * 32 + lane] = acc;
}

// GEMM: out[M x HOUT] = act( f(A[M x 128]) @ W[128 x HOUT] + bias )
// BN=64 col tiles; persistent blocks; 2 blocks/CU; register-prefetch
// pipeline: next tile's global loads issue before current tile's compute.
// ACT: 0 none, 1 relu, 2 sigmoid. RELU_IN: relu on A load.
// TAIL_HIST: run the edge histogram after the tile loop (independent work).
template <int HOUT, int ACT, bool RELU_IN, bool TAIL_HIST>
__global__ __launch_bounds__(256, 2) void k_gemm(
    const float* __restrict__ A, const float* __restrict__ W,
    const float* __restrict__ bias, float* __restrict__ out, int M,
    const int* __restrict__ hcol, int* __restrict__ hcnt,
    int* __restrict__ hrank, int E) {
  constexpr int NCT = HOUT / 64;   // column tiles
  constexpr int W4R = HOUT / 4;    // float4 per W row
  __shared__ float Ws[128 * 64];   // 32 KB
  __shared__ float Xs[64][132];    // 33 KB

  const int t = threadIdx.x;
  const int ct = blockIdx.x % NCT;
  const int rt0 = blockIdx.x / NCT;
  const int rstride = gridDim.x / NCT;
  const int ntiles = (M + 63) >> 6;

  for (int i = t; i < 128 * 16; i += 256) {
    int k = i >> 4, j4 = i & 15;
    ((float4*)Ws)[i] = ((const float4*)W)[k * W4R + ct * 16 + j4];
  }

  const int tc = t & 15;
  const int tr = t >> 4;
  const float4* A4 = (const float4*)A;
  const int r0 = t >> 5, c40 = t & 31;       // staging coords: 8 rows apart

  float4 pre[8];
  auto load_tile = [&](int rt) {
#pragma unroll
    for (int q = 0; q < 8; ++q) {
      int gr = (rt << 6) + r0 + q * 8;
      pre[q] = (gr < M) ? A4[(size_t)gr * 32 + c40]
                        : make_float4(0.f, 0.f, 0.f, 0.f);
    }
  };
  auto store_tile = [&]() {
#pragma unroll
    for (int q = 0; q < 8; ++q) {
      float4 v = pre[q];
      if (RELU_IN) {
        v.x = fmaxf(v.x, 0.f); v.y = fmaxf(v.y, 0.f);
        v.z = fmaxf(v.z, 0.f); v.w = fmaxf(v.w, 0.f);
      }
      *(float4*)&Xs[r0 + q * 8][c40 * 4] = v;
    }
  };

  if (rt0 < ntiles) {
    // prologue: stage first tile
    load_tile(rt0);
    __syncthreads();             // Ws staged (and Xs free)
    store_tile();
    __syncthreads();

    for (int rt = rt0; rt < ntiles; rt += rstride) {
      const int nxt = rt + rstride;
      if (nxt < ntiles) load_tile(nxt);   // issue next tile's loads NOW

      const int m0 = rt << 6;
      float acc[4][4];
#pragma unroll
      for (int rr = 0; rr < 4; ++rr)
        acc[rr][0] = acc[rr][1] = acc[rr][2] = acc[rr][3] = 0.f;

#pragma unroll 4
      for (int k4 = 0; k4 < 32; ++k4) {
        float4 wv[4], av[4];
#pragma unroll
        for (int kk = 0; kk < 4; ++kk)
          wv[kk] = ((const float4*)Ws)[(k4 * 4 + kk) * 16 + tc];
#pragma unroll
        for (int rr = 0; rr < 4; ++rr)
          av[rr] = *(const float4*)&Xs[tr * 4 + rr][k4 * 4];
#pragma unroll
        for (int rr = 0; rr < 4; ++rr) {
          acc[rr][0] = fmaf(av[rr].x, wv[0].x, acc[rr][0]);
          acc[rr][1] = fmaf(av[rr].x, wv[0].y, acc[rr][1]);
          acc[rr][2] = fmaf(av[rr].x, wv[0].z, acc[rr][2]);
          acc[rr][3] = fmaf(av[rr].x, wv[0].w, acc[rr][3]);
          acc[rr][0] = fmaf(av[rr].y, wv[1].x, acc[rr][0]);
          acc[rr][1] = fmaf(av[rr].y, wv[1].y, acc[rr][1]);
          acc[rr][2] = fmaf(av[rr].y, wv[1].z, acc[rr][2]);
          acc[rr][3] = fmaf(av[rr].y, wv[1].w, acc[rr][3]);
          acc[rr][0] = fmaf(av[rr].z, wv[2].x, acc[rr][0]);
          acc[rr][1] = fmaf(av[rr].z, wv[2].y, acc[rr][1]);
          acc[rr][2] = fmaf(av[rr].z, wv[2].z, acc[rr][2]);
          acc[rr][3] = fmaf(av[rr].z, wv[2].w, acc[rr][3]);
          acc[rr][0] = fmaf(av[rr].w, wv[3].x, acc[rr][0]);
          acc[rr][1] = fmaf(av[rr].w, wv[3].y, acc[rr][1]);
          acc[rr][2] = fmaf(av[rr].w, wv[3].z, acc[rr][2]);
          acc[rr][3] = fmaf(av[rr].w, wv[3].w, acc[rr][3]);
        }
      }

#pragma unroll
      for (int rr = 0; rr < 4; ++rr) {
        int gr = m0 + tr * 4 + rr;
        if (gr >= M) continue;
        float4 v = make_float4(acc[rr][0], acc[rr][1], acc[rr][2], acc[rr][3]);
        if (bias) {
          const float4 bv = *(const float4*)&bias[ct * 64 + tc * 4];
          v.x += bv.x; v.y += bv.y; v.z += bv.z; v.w += bv.w;
        }
        if (ACT == 1) {
          v.x = fmaxf(v.x, 0.f); v.y = fmaxf(v.y, 0.f);
          v.z = fmaxf(v.z, 0.f); v.w = fmaxf(v.w, 0.f);
        } else if (ACT == 2) {
          v.x = 1.f / (1.f + __expf(-v.x));
          v.y = 1.f / (1.f + __expf(-v.y));
          v.z = 1.f / (1.f + __expf(-v.z));
          v.w = 1.f / (1.f + __expf(-v.w));
        }
        ((float4*)out)[(size_t)gr * W4R + ct * 16 + tc] = v;
      }

      if (nxt < ntiles) {
        __syncthreads();         // all reads of Xs done
        store_tile();            // regs -> Xs for next tile
        __syncthreads();         // Xs ready
      }
    }
  }

  if (TAIL_HIST) {
    // independent edge histogram; rank = slot within target bucket
    const int gsz = gridDim.x * 256;
    for (int e = blockIdx.x * 256 + t; e < E; e += gsz)
      hrank[e] = atomicAdd(&hcnt[hcol[e]], 1);
  }
}

extern "C" void kernel_launch(void* const* d_in, const int* in_sizes, int n_in,
                              void* d_out, int out_size, void* d_ws, size_t ws_size,
                              hipStream_t stream) {
  const float* x        = (const float*)d_in[0];
  const float* edge_emb = (const float*)d_in[1];
  const float* W1 = (const float*)d_in[2];  const float* b1 = (const float*)d_in[3];
  const float* W2 = (const float*)d_in[4];  const float* b2 = (const float*)d_in[5];
  const float* W3 = (const float*)d_in[6];  const float* b3 = (const float*)d_in[7];
  const float* cW1 = (const float*)d_in[8]; const float* cb1 = (const float*)d_in[9];
  const float* cW2 = (const float*)d_in[10]; const float* cb2 = (const float*)d_in[11];
  const int* eidx  = (const int*)d_in[12];
  const int* eattr = (const int*)d_in[13];

  const int N = in_sizes[0] / 128;
  const int E = in_sizes[13];
  const int* row = eidx;        // edge_index[0] = source
  const int* col = eidx + E;    // edge_index[1] = target

  float* out = (float*)d_out;

  // workspace layout, 16B-aligned slots (element counts rounded to x4)
  size_t off = 0;
  auto alloc4 = [&](size_t n) { size_t o = off; off += (n + 3) & ~(size_t)3; return o; };
  float* wsf = (float*)d_ws;
  int*   wsi = (int*)d_ws;

  float* dinv   = wsf + alloc4(N);
  float* snorm  = wsf + alloc4(N);
  int*   cnt    = wsi + alloc4(N);
  int*   start  = wsi + alloc4(N + 1);
  int*   bsum   = wsi + alloc4(256);
  int*   rank   = wsi + alloc4(E);
  int*   srcs   = wsi + alloc4(E);
  float* wts    = wsf + alloc4(E);   // raw ew (deg pass), then normalized
  float* bufA   = wsf + alloc4((size_t)N * 128);
  float* bufB   = wsf + alloc4((size_t)N * 128);

  const int gN  = (N + 255) / 256;
  const int gE  = (E + 255) / 256;
  const int gA  = (N * 32 + 255) / 256;
  const int nb  = gN;  // scan blocks
  const int gGemm = 512;   // persistent: 2 blocks/CU

  // cnt must be zero before the hist tail in the layer-1 GEMM
  (void)hipMemsetAsync(cnt, 0, (size_t)N * sizeof(int), stream);

  // ---- layer-1 GEMM + edge histogram (independent, one dispatch) ----
  k_gemm<128, 0, false, true><<<gGemm, 256, 0, stream>>>(
      x, W1, nullptr, bufA, N, col, cnt, rank, E);

  // ---- CSR build (reused by all 3 layers) ----
  k_scan1<<<nb, 256, 0, stream>>>(cnt, start, bsum, N);
  k_scan2<<<1, 256, 0, stream>>>(bsum, nb);
  k_scan3<<<nb, 256, 0, stream>>>(start, bsum, N);
  k_fill<<<gE, 256, 0, stream>>>(eattr, edge_emb, row, col, rank, start,
                                 srcs, wts, E);
  k_deg_csr<<<gN, 256, 0, stream>>>(start, wts, dinv, snorm, N);
  k_wts_edge<<<gE, 256, 0, stream>>>(eattr, edge_emb, row, col, rank, start,
                                     dinv, wts, E);

  // ---- layer 1 agg ----
  k_agg_csr<<<gA, 256, 0, stream>>>(bufA, start, srcs, wts, snorm, b1, bufB, N);
  // ---- layer 2 ----
  k_gemm<128, 0, true, false><<<gGemm, 256, 0, stream>>>(
      bufB, W2, nullptr, bufA, N, nullptr, nullptr, nullptr, 0);
  k_agg_csr<<<gA, 256, 0, stream>>>(bufA, start, srcs, wts, snorm, b2, bufB, N);
  // ---- layer 3 ----
  k_gemm<128, 0, true, false><<<gGemm, 256, 0, stream>>>(
      bufB, W3, nullptr, bufA, N, nullptr, nullptr, nullptr, 0);
  k_agg_csr<<<gA, 256, 0, stream>>>(bufA, start, srcs, wts, snorm, b3, bufB, N);

  // ---- classifier ----
  k_gemm<128, 1, true, false><<<gGemm, 256, 0, stream>>>(
      bufB, cW1, cb1, bufA, N, nullptr, nullptr, nullptr, 0);
  k_gemm<64, 2, false, false><<<gGemm, 256, 0, stream>>>(
      bufA, cW2, cb2, out, N, nullptr, nullptr, nullptr, 0);
}

// Round 16
// 430.856 us; speedup vs baseline: 1.0464x; 1.0464x over previous
//
#include <hip/hip_runtime.h>
#include <cstdint>
#include <cstddef>

// ---------------------------------------------------------------------------
// CADGroupingGNN: 3x GCNConv(128->128) + MLP classifier, N=50000, E=800000.
// Round 16: interleaved hist. Round-14/15's tail-fused hist ran AFTER all
// tiles (zero overlap; 71us = gemm+hist serial). Now each thread issues 3
// edge-histogram atomics (returns kept in regs, unused) BEFORE each tile's
// compute and stores the ranks after it -- the vmcnt wait sinks past the
// 2048-FMA body, hiding the atomic latency. Agg stays at the proven round-6
// form (69us gather service floor). fp32 mandatory.
// ---------------------------------------------------------------------------

// ---- exclusive scan of cnt[] over N elements (3 kernels) ----
__global__ __launch_bounds__(256) void k_scan1(
    const int* __restrict__ cnt, int* __restrict__ start,
    int* __restrict__ bsum, int n) {
  __shared__ int s[256];
  int t = threadIdx.x, idx = blockIdx.x * 256 + t;
  s[t] = (idx < n) ? cnt[idx] : 0;
  for (int d = 1; d < 256; d <<= 1) {
    __syncthreads();
    int x = (t >= d) ? s[t - d] : 0;
    __syncthreads();
    s[t] += x;
  }
  __syncthreads();
  if (idx < n) start[idx + 1] = s[t];          // inclusive, per-block
  if (t == 255) bsum[blockIdx.x] = s[255];
}

__global__ __launch_bounds__(256) void k_scan2(int* __restrict__ bsum, int nb) {
  __shared__ int s[256];
  int t = threadIdx.x;
  s[t] = (t < nb) ? bsum[t] : 0;
  for (int d = 1; d < 256; d <<= 1) {
    __syncthreads();
    int x = (t >= d) ? s[t - d] : 0;
    __syncthreads();
    s[t] += x;
  }
  __syncthreads();
  if (t < nb) bsum[t] = s[t];                  // inclusive block sums
}

__global__ __launch_bounds__(256) void k_scan3(
    int* __restrict__ start, const int* __restrict__ bsum, int n) {
  int b = blockIdx.x, idx = b * 256 + threadIdx.x;
  if (idx < n) {
    int off = (b > 0) ? bsum[b - 1] : 0;
    start[idx + 1] += off;
    if (idx == 0) start[0] = 0;
  }
}

// atomic-free bucket fill: p = start[col] + rank; writes src index + raw ew
__global__ __launch_bounds__(256) void k_fill(
    const int* __restrict__ attr, const float* __restrict__ emb,
    const int* __restrict__ row, const int* __restrict__ col,
    const int* __restrict__ rank, const int* __restrict__ start,
    int* __restrict__ srcs, float* __restrict__ ew_s, int E) {
  int e = blockIdx.x * 256 + threadIdx.x;
  if (e < E) {
    int p = start[col[e]] + rank[e];
    srcs[p] = row[e];
    ew_s[p] = emb[attr[e]];
  }
}

// per-node deterministic degree sum (raw ew in wts) -> dinv, snorm
__global__ __launch_bounds__(256) void k_deg_csr(
    const int* __restrict__ start, const float* __restrict__ ew_s,
    float* __restrict__ dinv, float* __restrict__ snorm, int n) {
  int i = blockIdx.x * 256 + threadIdx.x;
  if (i >= n) return;
  int s = start[i], e = start[i + 1];
  float d = 1.0f;                              // self-loop weight
  for (int p = s; p < e; ++p) d += ew_s[p];
  float v = d > 0.f ? rsqrtf(d) : 0.f;
  dinv[i] = v;
  snorm[i] = v * v;
}

// edge-parallel weight normalization: wts[p] = dinv[row]*emb*dinv[col]
__global__ __launch_bounds__(256) void k_wts_edge(
    const int* __restrict__ attr, const float* __restrict__ emb,
    const int* __restrict__ row, const int* __restrict__ col,
    const int* __restrict__ rank, const int* __restrict__ start,
    const float* __restrict__ dinv, float* __restrict__ wts, int E) {
  int e = blockIdx.x * 256 + threadIdx.x;
  if (e < E) {
    int c = col[e];
    int p = start[c] + rank[e];
    wts[p] = dinv[row[e]] * emb[attr[e]] * dinv[c];
  }
}

__device__ __forceinline__ void agg_fma(float s, const float4& v, float4& acc) {
  acc.x = fmaf(s, v.x, acc.x);
  acc.y = fmaf(s, v.y, acc.y);
  acc.z = fmaf(s, v.z, acc.z);
  acc.w = fmaf(s, v.w, acc.w);
}

// out[i][:] = bias + snorm[i]*h[i][:] + sum_e wts[e]*h[srcs[e]][:]
// 32 lanes per node, float4 per lane (128 channels). 8-deep gather pipeline.
__global__ __launch_bounds__(256) void k_agg_csr(
    const float* __restrict__ h, const int* __restrict__ start,
    const int* __restrict__ srcs, const float* __restrict__ wts,
    const float* __restrict__ snorm, const float* __restrict__ bias,
    float* __restrict__ out, int n) {
  int tid = blockIdx.x * 256 + threadIdx.x;
  int i = tid >> 5;
  if (i >= n) return;
  int lane = tid & 31;
  const float4* h4 = (const float4*)h;
  float4 acc = ((const float4*)bias)[lane];
  float sn = snorm[i];
  float4 hv = h4[(size_t)i * 32 + lane];
  agg_fma(sn, hv, acc);

  int e = start[i], eend = start[i + 1];

  while (e < eend && (e & 3)) {
    float w = wts[e];
    float4 v = h4[(size_t)srcs[e] * 32 + lane];
    agg_fma(w, v, acc);
    ++e;
  }

  for (; e + 8 <= eend; e += 8) {
    int4   s0 = *(const int4*)&srcs[e];
    int4   s1 = *(const int4*)&srcs[e + 4];
    float4 w0 = *(const float4*)&wts[e];
    float4 w1 = *(const float4*)&wts[e + 4];
    float4 v0 = h4[(size_t)s0.x * 32 + lane];
    float4 v1 = h4[(size_t)s0.y * 32 + lane];
    float4 v2 = h4[(size_t)s0.z * 32 + lane];
    float4 v3 = h4[(size_t)s0.w * 32 + lane];
    float4 v4 = h4[(size_t)s1.x * 32 + lane];
    float4 v5 = h4[(size_t)s1.y * 32 + lane];
    float4 v6 = h4[(size_t)s1.z * 32 + lane];
    float4 v7 = h4[(size_t)s1.w * 32 + lane];
    agg_fma(w0.x, v0, acc); agg_fma(w0.y, v1, acc);
    agg_fma(w0.z, v2, acc); agg_fma(w0.w, v3, acc);
    agg_fma(w1.x, v4, acc); agg_fma(w1.y, v5, acc);
    agg_fma(w1.z, v6, acc); agg_fma(w1.w, v7, acc);
  }

  if (e + 4 <= eend) {
    int4   s0 = *(const int4*)&srcs[e];
    float4 w0 = *(const float4*)&wts[e];
    float4 v0 = h4[(size_t)s0.x * 32 + lane];
    float4 v1 = h4[(size_t)s0.y * 32 + lane];
    float4 v2 = h4[(size_t)s0.z * 32 + lane];
    float4 v3 = h4[(size_t)s0.w * 32 + lane];
    agg_fma(w0.x, v0, acc); agg_fma(w0.y, v1, acc);
    agg_fma(w0.z, v2, acc); agg_fma(w0.w, v3, acc);
    e += 4;
  }

  for (; e < eend; ++e) {
    float w = wts[e];
    float4 v = h4[(size_t)srcs[e] * 32 + lane];
    agg_fma(w, v, acc);
  }

  ((float4*)out)[(size_t)i * 32 + lane] = acc;
}

// GEMM: out[M x HOUT] = act( f(A[M x 128]) @ W[128 x HOUT] + bias )
// BN=64 col tiles; persistent blocks; 2 blocks/CU; register-prefetch
// pipeline. ACT: 0 none, 1 relu, 2 sigmoid. RELU_IN: relu on A load.
// HIST: interleave the edge histogram with the tile loop -- issue 3 edge
// atomics before each tile's compute, store ranks after (latency hidden).
template <int HOUT, int ACT, bool RELU_IN, bool HIST>
__global__ __launch_bounds__(256, 2) void k_gemm(
    const float* __restrict__ A, const float* __restrict__ W,
    const float* __restrict__ bias, float* __restrict__ out, int M,
    const int* __restrict__ hcol, int* __restrict__ hcnt,
    int* __restrict__ hrank, int E) {
  constexpr int NCT = HOUT / 64;   // column tiles
  constexpr int W4R = HOUT / 4;    // float4 per W row
  __shared__ float Ws[128 * 64];   // 32 KB
  __shared__ float Xs[64][132];    // 33 KB

  const int t = threadIdx.x;
  const int ct = blockIdx.x % NCT;
  const int rt0 = blockIdx.x / NCT;
  const int rstride = gridDim.x / NCT;
  const int ntiles = (M + 63) >> 6;

  for (int i = t; i < 128 * 16; i += 256) {
    int k = i >> 4, j4 = i & 15;
    ((float4*)Ws)[i] = ((const float4*)W)[k * W4R + ct * 16 + j4];
  }

  const int tc = t & 15;
  const int tr = t >> 4;
  const float4* A4 = (const float4*)A;
  const int r0 = t >> 5, c40 = t & 31;       // staging coords: 8 rows apart

  // histogram edge striding: thread g handles edges g, g+G, g+2G, ...
  const int g = blockIdx.x * 256 + t;
  const int G = gridDim.x * 256;
  int jtile = 0;                              // executed-tile counter

  float4 pre[8];
  auto load_tile = [&](int rt) {
#pragma unroll
    for (int q = 0; q < 8; ++q) {
      int gr = (rt << 6) + r0 + q * 8;
      pre[q] = (gr < M) ? A4[(size_t)gr * 32 + c40]
                        : make_float4(0.f, 0.f, 0.f, 0.f);
    }
  };
  auto store_tile = [&]() {
#pragma unroll
    for (int q = 0; q < 8; ++q) {
      float4 v = pre[q];
      if (RELU_IN) {
        v.x = fmaxf(v.x, 0.f); v.y = fmaxf(v.y, 0.f);
        v.z = fmaxf(v.z, 0.f); v.w = fmaxf(v.w, 0.f);
      }
      *(float4*)&Xs[r0 + q * 8][c40 * 4] = v;
    }
  };

  if (rt0 < ntiles) {
    load_tile(rt0);
    __syncthreads();             // Ws staged (and Xs free)
    store_tile();
    __syncthreads();

    for (int rt = rt0; rt < ntiles; rt += rstride) {
      const int nxt = rt + rstride;
      if (nxt < ntiles) load_tile(nxt);   // issue next tile's loads NOW

      // issue this tile's hist chunk (3 edges); returns unused until after
      int he0 = -1, he1 = -1, he2 = -1;
      int hr0 = 0, hr1 = 0, hr2 = 0;
      if (HIST) {
        int base = (jtile * 3) * G + g;
        if (base < E)         { he0 = base;         hr0 = atomicAdd(&hcnt[hcol[he0]], 1); }
        if (base + G < E)     { he1 = base + G;     hr1 = atomicAdd(&hcnt[hcol[he1]], 1); }
        if (base + 2 * G < E) { he2 = base + 2 * G; hr2 = atomicAdd(&hcnt[hcol[he2]], 1); }
      }

      const int m0 = rt << 6;
      float acc[4][4];
#pragma unroll
      for (int rr = 0; rr < 4; ++rr)
        acc[rr][0] = acc[rr][1] = acc[rr][2] = acc[rr][3] = 0.f;

#pragma unroll 4
      for (int k4 = 0; k4 < 32; ++k4) {
        float4 wv[4], av[4];
#pragma unroll
        for (int kk = 0; kk < 4; ++kk)
          wv[kk] = ((const float4*)Ws)[(k4 * 4 + kk) * 16 + tc];
#pragma unroll
        for (int rr = 0; rr < 4; ++rr)
          av[rr] = *(const float4*)&Xs[tr * 4 + rr][k4 * 4];
#pragma unroll
        for (int rr = 0; rr < 4; ++rr) {
          acc[rr][0] = fmaf(av[rr].x, wv[0].x, acc[rr][0]);
          acc[rr][1] = fmaf(av[rr].x, wv[0].y, acc[rr][1]);
          acc[rr][2] = fmaf(av[rr].x, wv[0].z, acc[rr][2]);
          acc[rr][3] = fmaf(av[rr].x, wv[0].w, acc[rr][3]);
          acc[rr][0] = fmaf(av[rr].y, wv[1].x, acc[rr][0]);
          acc[rr][1] = fmaf(av[rr].y, wv[1].y, acc[rr][1]);
          acc[rr][2] = fmaf(av[rr].y, wv[1].z, acc[rr][2]);
          acc[rr][3] = fmaf(av[rr].y, wv[1].w, acc[rr][3]);
          acc[rr][0] = fmaf(av[rr].z, wv[2].x, acc[rr][0]);
          acc[rr][1] = fmaf(av[rr].z, wv[2].y, acc[rr][1]);
          acc[rr][2] = fmaf(av[rr].z, wv[2].z, acc[rr][2]);
          acc[rr][3] = fmaf(av[rr].z, wv[2].w, acc[rr][3]);
          acc[rr][0] = fmaf(av[rr].w, wv[3].x, acc[rr][0]);
          acc[rr][1] = fmaf(av[rr].w, wv[3].y, acc[rr][1]);
          acc[rr][2] = fmaf(av[rr].w, wv[3].z, acc[rr][2]);
          acc[rr][3] = fmaf(av[rr].w, wv[3].w, acc[rr][3]);
        }
      }

#pragma unroll
      for (int rr = 0; rr < 4; ++rr) {
        int gr = m0 + tr * 4 + rr;
        if (gr >= M) continue;
        float4 v = make_float4(acc[rr][0], acc[rr][1], acc[rr][2], acc[rr][3]);
        if (bias) {
          const float4 bv = *(const float4*)&bias[ct * 64 + tc * 4];
          v.x += bv.x; v.y += bv.y; v.z += bv.z; v.w += bv.w;
        }
        if (ACT == 1) {
          v.x = fmaxf(v.x, 0.f); v.y = fmaxf(v.y, 0.f);
          v.z = fmaxf(v.z, 0.f); v.w = fmaxf(v.w, 0.f);
        } else if (ACT == 2) {
          v.x = 1.f / (1.f + __expf(-v.x));
          v.y = 1.f / (1.f + __expf(-v.y));
          v.z = 1.f / (1.f + __expf(-v.z));
          v.w = 1.f / (1.f + __expf(-v.w));
        }
        ((float4*)out)[(size_t)gr * W4R + ct * 16 + tc] = v;
      }

      if (HIST) {
        // atomic returns consumed here -- waitcnt sat behind the FMA body
        if (he0 >= 0) hrank[he0] = hr0;
        if (he1 >= 0) hrank[he1] = hr1;
        if (he2 >= 0) hrank[he2] = hr2;
        ++jtile;
      }

      if (nxt < ntiles) {
        __syncthreads();         // all reads of Xs done
        store_tile();            // regs -> Xs for next tile
        __syncthreads();         // Xs ready
      }
    }
  }

  if (HIST) {
    // robustness tail: any edges not covered by the in-loop chunks
    for (long long m = 3LL * jtile;; ++m) {
      long long e = m * G + g;
      if (e >= E) break;
      hrank[e] = atomicAdd(&hcnt[hcol[e]], 1);
    }
  }
}

extern "C" void kernel_launch(void* const* d_in, const int* in_sizes, int n_in,
                              void* d_out, int out_size, void* d_ws, size_t ws_size,
                              hipStream_t stream) {
  const float* x        = (const float*)d_in[0];
  const float* edge_emb = (const float*)d_in[1];
  const float* W1 = (const float*)d_in[2];  const float* b1 = (const float*)d_in[3];
  const float* W2 = (const float*)d_in[4];  const float* b2 = (const float*)d_in[5];
  const float* W3 = (const float*)d_in[6];  const float* b3 = (const float*)d_in[7];
  const float* cW1 = (const float*)d_in[8]; const float* cb1 = (const float*)d_in[9];
  const float* cW2 = (const float*)d_in[10]; const float* cb2 = (const float*)d_in[11];
  const int* eidx  = (const int*)d_in[12];
  const int* eattr = (const int*)d_in[13];

  const int N = in_sizes[0] / 128;
  const int E = in_sizes[13];
  const int* row = eidx;        // edge_index[0] = source
  const int* col = eidx + E;    // edge_index[1] = target

  float* out = (float*)d_out;

  // workspace layout, 16B-aligned slots (element counts rounded to x4)
  size_t off = 0;
  auto alloc4 = [&](size_t n) { size_t o = off; off += (n + 3) & ~(size_t)3; return o; };
  float* wsf = (float*)d_ws;
  int*   wsi = (int*)d_ws;

  float* dinv   = wsf + alloc4(N);
  float* snorm  = wsf + alloc4(N);
  int*   cnt    = wsi + alloc4(N);
  int*   start  = wsi + alloc4(N + 1);
  int*   bsum   = wsi + alloc4(256);
  int*   rank   = wsi + alloc4(E);
  int*   srcs   = wsi + alloc4(E);
  float* wts    = wsf + alloc4(E);   // raw ew (deg pass), then normalized
  float* bufA   = wsf + alloc4((size_t)N * 128);
  float* bufB   = wsf + alloc4((size_t)N * 128);

  const int gN  = (N + 255) / 256;
  const int gE  = (E + 255) / 256;
  const int gA  = (N * 32 + 255) / 256;
  const int nb  = gN;  // scan blocks
  const int gGemm = 512;   // persistent: 2 blocks/CU

  // cnt must be zero before the interleaved hist in the layer-1 GEMM
  (void)hipMemsetAsync(cnt, 0, (size_t)N * sizeof(int), stream);

  // ---- layer-1 GEMM with interleaved edge histogram (one dispatch) ----
  k_gemm<128, 0, false, true><<<gGemm, 256, 0, stream>>>(
      x, W1, nullptr, bufA, N, col, cnt, rank, E);

  // ---- CSR build (reused by all 3 layers) ----
  k_scan1<<<nb, 256, 0, stream>>>(cnt, start, bsum, N);
  k_scan2<<<1, 256, 0, stream>>>(bsum, nb);
  k_scan3<<<nb, 256, 0, stream>>>(start, bsum, N);
  k_fill<<<gE, 256, 0, stream>>>(eattr, edge_emb, row, col, rank, start,
                                 srcs, wts, E);
  k_deg_csr<<<gN, 256, 0, stream>>>(start, wts, dinv, snorm, N);
  k_wts_edge<<<gE, 256, 0, stream>>>(eattr, edge_emb, row, col, rank, start,
                                     dinv, wts, E);

  // ---- layer 1 agg ----
  k_agg_csr<<<gA, 256, 0, stream>>>(bufA, start, srcs, wts, snorm, b1, bufB, N);
  // ---- layer 2 ----
  k_gemm<128, 0, true, false><<<gGemm, 256, 0, stream>>>(
      bufB, W2, nullptr, bufA, N, nullptr, nullptr, nullptr, 0);
  k_agg_csr<<<gA, 256, 0, stream>>>(bufA, start, srcs, wts, snorm, b2, bufB, N);
  // ---- layer 3 ----
  k_gemm<128, 0, true, false><<<gGemm, 256, 0, stream>>>(
      bufB, W3, nullptr, bufA, N, nullptr, nullptr, nullptr, 0);
  k_agg_csr<<<gA, 256, 0, stream>>>(bufA, start, srcs, wts, snorm, b3, bufB, N);

  // ---- classifier ----
  k_gemm<128, 1, true, false><<<gGemm, 256, 0, stream>>>(
      bufB, cW1, cb1, bufA, N, nullptr, nullptr, nullptr, 0);
  k_gemm<64, 2, false, false><<<gGemm, 256, 0, stream>>>(
      bufA, cW2, cb2, out, N, nullptr, nullptr, nullptr, 0);
}

// Round 17
// 426.368 us; speedup vs baseline: 1.0574x; 1.0105x over previous
//
#include <hip/hip_runtime.h>
#include <cstdint>
#include <cstddef>

// ---------------------------------------------------------------------------
// CADGroupingGNN: 3x GCNConv(128->128) + MLP classifier, N=50000, E=800000.
// Round 17:
//  - packed 3-field histogram (attr in {0,1,2}): one atomic yields per-attr
//    counts -> deg computed in scan1 (no k_deg_csr), fill writes final
//    normalized wts (no k_wts_edge). 2 dispatches removed.
//  - classifier MLP fused into one kernel (129KB LDS, 1 block/CU): GEMM1 ->
//    c1 in LDS -> GEMM2 -> sigmoid out. Kills 51MB round-trip + 1 dispatch.
// Agg unchanged (69us gather service floor). fp32 mandatory.
// ---------------------------------------------------------------------------

// ---- scan1: unpack counts, compute deg/dinv/snorm, block-scan totals ----
__global__ __launch_bounds__(256) void k_scan1(
    const int* __restrict__ cnt, int* __restrict__ start,
    int* __restrict__ bsum, const float* __restrict__ emb,
    float* __restrict__ dinv, float* __restrict__ snorm, int n) {
  __shared__ int s[256];
  int t = threadIdx.x, idx = blockIdx.x * 256 + t;
  int packed = (idx < n) ? cnt[idx] : 0;
  int c0 = packed & 1023, c1 = (packed >> 10) & 1023, c2 = (packed >> 20) & 1023;
  if (idx < n) {
    float deg = 1.0f + (float)c0 * emb[0] + (float)c1 * emb[1]
                     + (float)c2 * emb[2];
    float v = deg > 0.f ? rsqrtf(deg) : 0.f;
    dinv[idx] = v;
    snorm[idx] = v * v;
  }
  s[t] = c0 + c1 + c2;
  for (int d = 1; d < 256; d <<= 1) {
    __syncthreads();
    int x = (t >= d) ? s[t - d] : 0;
    __syncthreads();
    s[t] += x;
  }
  __syncthreads();
  if (idx < n) start[idx + 1] = s[t];          // inclusive, per-block
  if (t == 255) bsum[blockIdx.x] = s[255];
}

__global__ __launch_bounds__(256) void k_scan2(int* __restrict__ bsum, int nb) {
  __shared__ int s[256];
  int t = threadIdx.x;
  s[t] = (t < nb) ? bsum[t] : 0;
  for (int d = 1; d < 256; d <<= 1) {
    __syncthreads();
    int x = (t >= d) ? s[t - d] : 0;
    __syncthreads();
    s[t] += x;
  }
  __syncthreads();
  if (t < nb) bsum[t] = s[t];                  // inclusive block sums
}

__global__ __launch_bounds__(256) void k_scan3(
    int* __restrict__ start, const int* __restrict__ bsum, int n) {
  int b = blockIdx.x, idx = b * 256 + threadIdx.x;
  if (idx < n) {
    int off = (b > 0) ? bsum[b - 1] : 0;
    start[idx + 1] += off;
    if (idx == 0) start[0] = 0;
  }
}

// atomic-free bucket fill: p = start[col] + rank; writes src + FINAL weight
__global__ __launch_bounds__(256) void k_fill(
    const int* __restrict__ attr, const float* __restrict__ emb,
    const int* __restrict__ row, const int* __restrict__ col,
    const int* __restrict__ rank, const int* __restrict__ start,
    const float* __restrict__ dinv, int* __restrict__ srcs,
    float* __restrict__ wts, int E) {
  int e = blockIdx.x * 256 + threadIdx.x;
  if (e < E) {
    int r = row[e], c = col[e];
    int p = start[c] + rank[e];
    srcs[p] = r;
    wts[p] = dinv[r] * emb[attr[e]] * dinv[c];
  }
}

__device__ __forceinline__ void agg_fma(float s, const float4& v, float4& acc) {
  acc.x = fmaf(s, v.x, acc.x);
  acc.y = fmaf(s, v.y, acc.y);
  acc.z = fmaf(s, v.z, acc.z);
  acc.w = fmaf(s, v.w, acc.w);
}

// out[i][:] = bias + snorm[i]*h[i][:] + sum_e wts[e]*h[srcs[e]][:]
// 32 lanes per node, float4 per lane (128 channels). 8-deep gather pipeline.
__global__ __launch_bounds__(256) void k_agg_csr(
    const float* __restrict__ h, const int* __restrict__ start,
    const int* __restrict__ srcs, const float* __restrict__ wts,
    const float* __restrict__ snorm, const float* __restrict__ bias,
    float* __restrict__ out, int n) {
  int tid = blockIdx.x * 256 + threadIdx.x;
  int i = tid >> 5;
  if (i >= n) return;
  int lane = tid & 31;
  const float4* h4 = (const float4*)h;
  float4 acc = ((const float4*)bias)[lane];
  float sn = snorm[i];
  float4 hv = h4[(size_t)i * 32 + lane];
  agg_fma(sn, hv, acc);

  int e = start[i], eend = start[i + 1];

  while (e < eend && (e & 3)) {
    float w = wts[e];
    float4 v = h4[(size_t)srcs[e] * 32 + lane];
    agg_fma(w, v, acc);
    ++e;
  }

  for (; e + 8 <= eend; e += 8) {
    int4   s0 = *(const int4*)&srcs[e];
    int4   s1 = *(const int4*)&srcs[e + 4];
    float4 w0 = *(const float4*)&wts[e];
    float4 w1 = *(const float4*)&wts[e + 4];
    float4 v0 = h4[(size_t)s0.x * 32 + lane];
    float4 v1 = h4[(size_t)s0.y * 32 + lane];
    float4 v2 = h4[(size_t)s0.z * 32 + lane];
    float4 v3 = h4[(size_t)s0.w * 32 + lane];
    float4 v4 = h4[(size_t)s1.x * 32 + lane];
    float4 v5 = h4[(size_t)s1.y * 32 + lane];
    float4 v6 = h4[(size_t)s1.z * 32 + lane];
    float4 v7 = h4[(size_t)s1.w * 32 + lane];
    agg_fma(w0.x, v0, acc); agg_fma(w0.y, v1, acc);
    agg_fma(w0.z, v2, acc); agg_fma(w0.w, v3, acc);
    agg_fma(w1.x, v4, acc); agg_fma(w1.y, v5, acc);
    agg_fma(w1.z, v6, acc); agg_fma(w1.w, v7, acc);
  }

  if (e + 4 <= eend) {
    int4   s0 = *(const int4*)&srcs[e];
    float4 w0 = *(const float4*)&wts[e];
    float4 v0 = h4[(size_t)s0.x * 32 + lane];
    float4 v1 = h4[(size_t)s0.y * 32 + lane];
    float4 v2 = h4[(size_t)s0.z * 32 + lane];
    float4 v3 = h4[(size_t)s0.w * 32 + lane];
    agg_fma(w0.x, v0, acc); agg_fma(w0.y, v1, acc);
    agg_fma(w0.z, v2, acc); agg_fma(w0.w, v3, acc);
    e += 4;
  }

  for (; e < eend; ++e) {
    float w = wts[e];
    float4 v = h4[(size_t)srcs[e] * 32 + lane];
    agg_fma(w, v, acc);
  }

  ((float4*)out)[(size_t)i * 32 + lane] = acc;
}

// GEMM: out[M x 128] = f(A) @ W.  BN=64 col tiles; persistent; 2 blocks/CU.
// RELU_IN: relu on A load. HIST: interleave packed edge histogram with the
// tile loop (atomic 1<<(10*attr); field-sum of old value = in-bucket rank).
template <bool RELU_IN, bool HIST>
__global__ __launch_bounds__(256, 2) void k_gemm(
    const float* __restrict__ A, const float* __restrict__ W,
    float* __restrict__ out, int M,
    const int* __restrict__ hcol, const int* __restrict__ hattr,
    int* __restrict__ hcnt, int* __restrict__ hrank, int E) {
  __shared__ float Ws[128 * 64];   // 32 KB
  __shared__ float Xs[64][132];    // 33 KB

  const int t = threadIdx.x;
  const int ct = blockIdx.x % 2;
  const int rt0 = blockIdx.x / 2;
  const int rstride = gridDim.x / 2;
  const int ntiles = (M + 63) >> 6;

  for (int i = t; i < 128 * 16; i += 256) {
    int k = i >> 4, j4 = i & 15;
    ((float4*)Ws)[i] = ((const float4*)W)[k * 32 + ct * 16 + j4];
  }

  const int tc = t & 15;
  const int tr = t >> 4;
  const float4* A4 = (const float4*)A;
  const int r0 = t >> 5, c40 = t & 31;

  const int g = blockIdx.x * 256 + t;
  const int G = gridDim.x * 256;
  int jtile = 0;

  float4 pre[8];
  auto load_tile = [&](int rt) {
#pragma unroll
    for (int q = 0; q < 8; ++q) {
      int gr = (rt << 6) + r0 + q * 8;
      pre[q] = (gr < M) ? A4[(size_t)gr * 32 + c40]
                        : make_float4(0.f, 0.f, 0.f, 0.f);
    }
  };
  auto store_tile = [&]() {
#pragma unroll
    for (int q = 0; q < 8; ++q) {
      float4 v = pre[q];
      if (RELU_IN) {
        v.x = fmaxf(v.x, 0.f); v.y = fmaxf(v.y, 0.f);
        v.z = fmaxf(v.z, 0.f); v.w = fmaxf(v.w, 0.f);
      }
      *(float4*)&Xs[r0 + q * 8][c40 * 4] = v;
    }
  };

  if (rt0 < ntiles) {
    load_tile(rt0);
    __syncthreads();
    store_tile();
    __syncthreads();

    for (int rt = rt0; rt < ntiles; rt += rstride) {
      const int nxt = rt + rstride;
      if (nxt < ntiles) load_tile(nxt);

      int he0 = -1, he1 = -1, he2 = -1;
      int hr0 = 0, hr1 = 0, hr2 = 0;
      if (HIST) {
        int base = (jtile * 3) * G + g;
        if (base < E) {
          he0 = base;
          hr0 = atomicAdd(&hcnt[hcol[he0]], 1 << (10 * hattr[he0]));
        }
        if (base + G < E) {
          he1 = base + G;
          hr1 = atomicAdd(&hcnt[hcol[he1]], 1 << (10 * hattr[he1]));
        }
        if (base + 2 * G < E) {
          he2 = base + 2 * G;
          hr2 = atomicAdd(&hcnt[hcol[he2]], 1 << (10 * hattr[he2]));
        }
      }

      const int m0 = rt << 6;
      float acc[4][4];
#pragma unroll
      for (int rr = 0; rr < 4; ++rr)
        acc[rr][0] = acc[rr][1] = acc[rr][2] = acc[rr][3] = 0.f;

#pragma unroll 4
      for (int k4 = 0; k4 < 32; ++k4) {
        float4 wv[4], av[4];
#pragma unroll
        for (int kk = 0; kk < 4; ++kk)
          wv[kk] = ((const float4*)Ws)[(k4 * 4 + kk) * 16 + tc];
#pragma unroll
        for (int rr = 0; rr < 4; ++rr)
          av[rr] = *(const float4*)&Xs[tr * 4 + rr][k4 * 4];
#pragma unroll
        for (int rr = 0; rr < 4; ++rr) {
          acc[rr][0] = fmaf(av[rr].x, wv[0].x, acc[rr][0]);
          acc[rr][1] = fmaf(av[rr].x, wv[0].y, acc[rr][1]);
          acc[rr][2] = fmaf(av[rr].x, wv[0].z, acc[rr][2]);
          acc[rr][3] = fmaf(av[rr].x, wv[0].w, acc[rr][3]);
          acc[rr][0] = fmaf(av[rr].y, wv[1].x, acc[rr][0]);
          acc[rr][1] = fmaf(av[rr].y, wv[1].y, acc[rr][1]);
          acc[rr][2] = fmaf(av[rr].y, wv[1].z, acc[rr][2]);
          acc[rr][3] = fmaf(av[rr].y, wv[1].w, acc[rr][3]);
          acc[rr][0] = fmaf(av[rr].z, wv[2].x, acc[rr][0]);
          acc[rr][1] = fmaf(av[rr].z, wv[2].y, acc[rr][1]);
          acc[rr][2] = fmaf(av[rr].z, wv[2].z, acc[rr][2]);
          acc[rr][3] = fmaf(av[rr].z, wv[2].w, acc[rr][3]);
          acc[rr][0] = fmaf(av[rr].w, wv[3].x, acc[rr][0]);
          acc[rr][1] = fmaf(av[rr].w, wv[3].y, acc[rr][1]);
          acc[rr][2] = fmaf(av[rr].w, wv[3].z, acc[rr][2]);
          acc[rr][3] = fmaf(av[rr].w, wv[3].w, acc[rr][3]);
        }
      }

#pragma unroll
      for (int rr = 0; rr < 4; ++rr) {
        int gr = m0 + tr * 4 + rr;
        if (gr >= M) continue;
        float4 v = make_float4(acc[rr][0], acc[rr][1], acc[rr][2], acc[rr][3]);
        ((float4*)out)[(size_t)gr * 32 + ct * 16 + tc] = v;
      }

      if (HIST) {
        // atomic returns consumed here; field-sum = dense in-bucket rank
        if (he0 >= 0)
          hrank[he0] = (hr0 & 1023) + ((hr0 >> 10) & 1023) + ((hr0 >> 20) & 1023);
        if (he1 >= 0)
          hrank[he1] = (hr1 & 1023) + ((hr1 >> 10) & 1023) + ((hr1 >> 20) & 1023);
        if (he2 >= 0)
          hrank[he2] = (hr2 & 1023) + ((hr2 >> 10) & 1023) + ((hr2 >> 20) & 1023);
        ++jtile;
      }

      if (nxt < ntiles) {
        __syncthreads();
        store_tile();
        __syncthreads();
      }
    }
  }

  if (HIST) {
    for (long long m = 3LL * jtile;; ++m) {
      long long e = m * G + g;
      if (e >= E) break;
      int a = hattr[e];
      int old = atomicAdd(&hcnt[hcol[e]], 1 << (10 * a));
      hrank[e] = (old & 1023) + ((old >> 10) & 1023) + ((old >> 20) & 1023);
    }
  }
}

// Fused classifier: out = sigmoid( relu( relu(A) @ W1 + b1 ) @ W2 + b2 )
// 129 KB LDS, 1 block/CU, 256 threads, persistent over 64-row tiles.
__global__ __launch_bounds__(256, 1) void k_classifier(
    const float* __restrict__ A, const float* __restrict__ W1,
    const float* __restrict__ b1, const float* __restrict__ W2,
    const float* __restrict__ b2, float* __restrict__ out, int M) {
  __shared__ float Ws1[128 * 128];   // 64 KB
  __shared__ float Ws2[128 * 64];    // 32 KB
  __shared__ float Xs[64][132];      // 33 KB

  const int t = threadIdx.x;
  for (int i = t; i < 128 * 32; i += 256)
    ((float4*)Ws1)[i] = ((const float4*)W1)[i];
  for (int i = t; i < 128 * 16; i += 256)
    ((float4*)Ws2)[i] = ((const float4*)W2)[i];

  const int ntiles = (M + 63) >> 6;
  const float4* A4 = (const float4*)A;
  const int r0 = t >> 5, c40 = t & 31;     // staging coords
  const int tc1 = t & 31, tr1 = t >> 5;    // GEMM1: 32 colgrp x 8 rowgrp(8 rows)
  const int tc2 = t & 15, tr2 = t >> 4;    // GEMM2: 16 colgrp x 16 rowgrp(4 rows)

  for (int rt = blockIdx.x; rt < ntiles; rt += gridDim.x) {
    const int m0 = rt << 6;
    __syncthreads();   // Ws staged (1st iter) / prev GEMM2 reads done

    // stage input tile with relu
#pragma unroll
    for (int q = 0; q < 8; ++q) {
      int gr = m0 + r0 + q * 8;
      float4 v = (gr < M) ? A4[(size_t)gr * 32 + c40]
                          : make_float4(0.f, 0.f, 0.f, 0.f);
      v.x = fmaxf(v.x, 0.f); v.y = fmaxf(v.y, 0.f);
      v.z = fmaxf(v.z, 0.f); v.w = fmaxf(v.w, 0.f);
      *(float4*)&Xs[r0 + q * 8][c40 * 4] = v;
    }
    __syncthreads();

    // GEMM1: c1[64][128]; this thread: rows tr1*8..+7, cols tc1*4..+3
    float4 acc1[8];
#pragma unroll
    for (int rr = 0; rr < 8; ++rr)
      acc1[rr] = make_float4(0.f, 0.f, 0.f, 0.f);

#pragma unroll 2
    for (int k4 = 0; k4 < 32; ++k4) {
      float4 wv[4], av[8];
#pragma unroll
      for (int kk = 0; kk < 4; ++kk)
        wv[kk] = ((const float4*)Ws1)[(k4 * 4 + kk) * 32 + tc1];
#pragma unroll
      for (int rr = 0; rr < 8; ++rr)
        av[rr] = *(const float4*)&Xs[tr1 * 8 + rr][k4 * 4];
#pragma unroll
      for (int rr = 0; rr < 8; ++rr) {
        acc1[rr].x = fmaf(av[rr].x, wv[0].x, acc1[rr].x);
        acc1[rr].y = fmaf(av[rr].x, wv[0].y, acc1[rr].y);
        acc1[rr].z = fmaf(av[rr].x, wv[0].z, acc1[rr].z);
        acc1[rr].w = fmaf(av[rr].x, wv[0].w, acc1[rr].w);
        acc1[rr].x = fmaf(av[rr].y, wv[1].x, acc1[rr].x);
        acc1[rr].y = fmaf(av[rr].y, wv[1].y, acc1[rr].y);
        acc1[rr].z = fmaf(av[rr].y, wv[1].z, acc1[rr].z);
        acc1[rr].w = fmaf(av[rr].y, wv[1].w, acc1[rr].w);
        acc1[rr].x = fmaf(av[rr].z, wv[2].x, acc1[rr].x);
        acc1[rr].y = fmaf(av[rr].z, wv[2].y, acc1[rr].y);
        acc1[rr].z = fmaf(av[rr].z, wv[2].z, acc1[rr].z);
        acc1[rr].w = fmaf(av[rr].z, wv[2].w, acc1[rr].w);
        acc1[rr].x = fmaf(av[rr].w, wv[3].x, acc1[rr].x);
        acc1[rr].y = fmaf(av[rr].w, wv[3].y, acc1[rr].y);
        acc1[rr].z = fmaf(av[rr].w, wv[3].z, acc1[rr].z);
        acc1[rr].w = fmaf(av[rr].w, wv[3].w, acc1[rr].w);
      }
    }

    // bias + relu
    const float4 bv1 = ((const float4*)b1)[tc1];
#pragma unroll
    for (int rr = 0; rr < 8; ++rr) {
      acc1[rr].x = fmaxf(acc1[rr].x + bv1.x, 0.f);
      acc1[rr].y = fmaxf(acc1[rr].y + bv1.y, 0.f);
      acc1[rr].z = fmaxf(acc1[rr].z + bv1.z, 0.f);
      acc1[rr].w = fmaxf(acc1[rr].w + bv1.w, 0.f);
    }

    __syncthreads();   // all GEMM1 reads of Xs done
#pragma unroll
    for (int rr = 0; rr < 8; ++rr)
      *(float4*)&Xs[tr1 * 8 + rr][tc1 * 4] = acc1[rr];
    __syncthreads();   // c1 ready

    // GEMM2: out[64][64]; this thread: rows tr2*4..+3, cols tc2*4..+3
    float4 acc2[4];
#pragma unroll
    for (int rr = 0; rr < 4; ++rr)
      acc2[rr] = make_float4(0.f, 0.f, 0.f, 0.f);

#pragma unroll 4
    for (int k4 = 0; k4 < 32; ++k4) {
      float4 wv[4], av[4];
#pragma unroll
      for (int kk = 0; kk < 4; ++kk)
        wv[kk] = ((const float4*)Ws2)[(k4 * 4 + kk) * 16 + tc2];
#pragma unroll
      for (int rr = 0; rr < 4; ++rr)
        av[rr] = *(const float4*)&Xs[tr2 * 4 + rr][k4 * 4];
#pragma unroll
      for (int rr = 0; rr < 4; ++rr) {
        acc2[rr].x = fmaf(av[rr].x, wv[0].x, acc2[rr].x);
        acc2[rr].y = fmaf(av[rr].x, wv[0].y, acc2[rr].y);
        acc2[rr].z = fmaf(av[rr].x, wv[0].z, acc2[rr].z);
        acc2[rr].w = fmaf(av[rr].x, wv[0].w, acc2[rr].w);
        acc2[rr].x = fmaf(av[rr].y, wv[1].x, acc2[rr].x);
        acc2[rr].y = fmaf(av[rr].y, wv[1].y, acc2[rr].y);
        acc2[rr].z = fmaf(av[rr].y, wv[1].z, acc2[rr].z);
        acc2[rr].w = fmaf(av[rr].y, wv[1].w, acc2[rr].w);
        acc2[rr].x = fmaf(av[rr].z, wv[2].x, acc2[rr].x);
        acc2[rr].y = fmaf(av[rr].z, wv[2].y, acc2[rr].y);
        acc2[rr].z = fmaf(av[rr].z, wv[2].z, acc2[rr].z);
        acc2[rr].w = fmaf(av[rr].z, wv[2].w, acc2[rr].w);
        acc2[rr].x = fmaf(av[rr].w, wv[3].x, acc2[rr].x);
        acc2[rr].y = fmaf(av[rr].w, wv[3].y, acc2[rr].y);
        acc2[rr].z = fmaf(av[rr].w, wv[3].z, acc2[rr].z);
        acc2[rr].w = fmaf(av[rr].w, wv[3].w, acc2[rr].w);
      }
    }

    const float4 bv2 = ((const float4*)b2)[tc2];
#pragma unroll
    for (int rr = 0; rr < 4; ++rr) {
      int gr = m0 + tr2 * 4 + rr;
      if (gr >= M) continue;
      float4 v;
      v.x = 1.f / (1.f + __expf(-(acc2[rr].x + bv2.x)));
      v.y = 1.f / (1.f + __expf(-(acc2[rr].y + bv2.y)));
      v.z = 1.f / (1.f + __expf(-(acc2[rr].z + bv2.z)));
      v.w = 1.f / (1.f + __expf(-(acc2[rr].w + bv2.w)));
      ((float4*)out)[(size_t)gr * 16 + tc2] = v;
    }
  }
}

extern "C" void kernel_launch(void* const* d_in, const int* in_sizes, int n_in,
                              void* d_out, int out_size, void* d_ws, size_t ws_size,
                              hipStream_t stream) {
  const float* x        = (const float*)d_in[0];
  const float* edge_emb = (const float*)d_in[1];
  const float* W1 = (const float*)d_in[2];  const float* b1 = (const float*)d_in[3];
  const float* W2 = (const float*)d_in[4];  const float* b2 = (const float*)d_in[5];
  const float* W3 = (const float*)d_in[6];  const float* b3 = (const float*)d_in[7];
  const float* cW1 = (const float*)d_in[8]; const float* cb1 = (const float*)d_in[9];
  const float* cW2 = (const float*)d_in[10]; const float* cb2 = (const float*)d_in[11];
  const int* eidx  = (const int*)d_in[12];
  const int* eattr = (const int*)d_in[13];

  const int N = in_sizes[0] / 128;
  const int E = in_sizes[13];
  const int* row = eidx;        // edge_index[0] = source
  const int* col = eidx + E;    // edge_index[1] = target

  float* out = (float*)d_out;

  // workspace layout, 16B-aligned slots (element counts rounded to x4)
  size_t off = 0;
  auto alloc4 = [&](size_t n) { size_t o = off; off += (n + 3) & ~(size_t)3; return o; };
  float* wsf = (float*)d_ws;
  int*   wsi = (int*)d_ws;

  float* dinv   = wsf + alloc4(N);
  float* snorm  = wsf + alloc4(N);
  int*   cnt    = wsi + alloc4(N);       // packed 3x10-bit per-attr counts
  int*   start  = wsi + alloc4(N + 1);
  int*   bsum   = wsi + alloc4(256);
  int*   rank   = wsi + alloc4(E);
  int*   srcs   = wsi + alloc4(E);
  float* wts    = wsf + alloc4(E);       // final normalized weights
  float* bufA   = wsf + alloc4((size_t)N * 128);
  float* bufB   = wsf + alloc4((size_t)N * 128);

  const int gN  = (N + 255) / 256;
  const int gE  = (E + 255) / 256;
  const int gA  = (N * 32 + 255) / 256;
  const int nb  = gN;  // scan blocks
  const int gGemm = 512;   // persistent: 2 blocks/CU
  const int gCls  = 256;   // classifier: 1 block/CU

  // cnt must be zero before the interleaved hist in the layer-1 GEMM
  (void)hipMemsetAsync(cnt, 0, (size_t)N * sizeof(int), stream);

  // ---- layer-1 GEMM with interleaved packed edge histogram ----
  k_gemm<false, true><<<gGemm, 256, 0, stream>>>(
      x, W1, bufA, N, col, eattr, cnt, rank, E);

  // ---- CSR build: scan (+deg/dinv/snorm inline) -> fill (normalized) ----
  k_scan1<<<nb, 256, 0, stream>>>(cnt, start, bsum, edge_emb, dinv, snorm, N);
  k_scan2<<<1, 256, 0, stream>>>(bsum, nb);
  k_scan3<<<nb, 256, 0, stream>>>(start, bsum, N);
  k_fill<<<gE, 256, 0, stream>>>(eattr, edge_emb, row, col, rank, start,
                                 dinv, srcs, wts, E);

  // ---- layer 1 agg ----
  k_agg_csr<<<gA, 256, 0, stream>>>(bufA, start, srcs, wts, snorm, b1, bufB, N);
  // ---- layer 2 ----
  k_gemm<true, false><<<gGemm, 256, 0, stream>>>(
      bufB, W2, bufA, N, nullptr, nullptr, nullptr, nullptr, 0);
  k_agg_csr<<<gA, 256, 0, stream>>>(bufA, start, srcs, wts, snorm, b2, bufB, N);
  // ---- layer 3 ----
  k_gemm<true, false><<<gGemm, 256, 0, stream>>>(
      bufB, W3, bufA, N, nullptr, nullptr, nullptr, nullptr, 0);
  k_agg_csr<<<gA, 256, 0, stream>>>(bufA, start, srcs, wts, snorm, b3, bufB, N);

  // ---- fused classifier ----
  k_classifier<<<gCls, 256, 0, stream>>>(bufB, cW1, cb1, cW2, cb2, out, N);
}

// Round 18
// 409.819 us; speedup vs baseline: 1.1001x; 1.0404x over previous
//
#include <hip/hip_runtime.h>
#include <cstdint>
#include <cstddef>

// ---------------------------------------------------------------------------
// CADGroupingGNN: 3x GCNConv(128->128) + MLP classifier, N=50000, E=800000.
// Round 18: keep round-17's packed 3-field histogram (attr in {0,1,2} ->
// per-attr counts in one atomic; deg/dinv/snorm inline in scan1; fill writes
// final normalized weights). REVERT the fused classifier: 1-block/CU 129KB
// kernel ran at 9% occupancy (85us vs 42us) -- third confirmation that
// mega-LDS 1-block/CU shapes lose on this chip. Two k_gemm dispatches again.
// Agg unchanged (69us gather service floor). fp32 mandatory.
// ---------------------------------------------------------------------------

// ---- scan1: unpack counts, compute deg/dinv/snorm, block-scan totals ----
__global__ __launch_bounds__(256) void k_scan1(
    const int* __restrict__ cnt, int* __restrict__ start,
    int* __restrict__ bsum, const float* __restrict__ emb,
    float* __restrict__ dinv, float* __restrict__ snorm, int n) {
  __shared__ int s[256];
  int t = threadIdx.x, idx = blockIdx.x * 256 + t;
  int packed = (idx < n) ? cnt[idx] : 0;
  int c0 = packed & 1023, c1 = (packed >> 10) & 1023, c2 = (packed >> 20) & 1023;
  if (idx < n) {
    float deg = 1.0f + (float)c0 * emb[0] + (float)c1 * emb[1]
                     + (float)c2 * emb[2];
    float v = deg > 0.f ? rsqrtf(deg) : 0.f;
    dinv[idx] = v;
    snorm[idx] = v * v;
  }
  s[t] = c0 + c1 + c2;
  for (int d = 1; d < 256; d <<= 1) {
    __syncthreads();
    int x = (t >= d) ? s[t - d] : 0;
    __syncthreads();
    s[t] += x;
  }
  __syncthreads();
  if (idx < n) start[idx + 1] = s[t];          // inclusive, per-block
  if (t == 255) bsum[blockIdx.x] = s[255];
}

__global__ __launch_bounds__(256) void k_scan2(int* __restrict__ bsum, int nb) {
  __shared__ int s[256];
  int t = threadIdx.x;
  s[t] = (t < nb) ? bsum[t] : 0;
  for (int d = 1; d < 256; d <<= 1) {
    __syncthreads();
    int x = (t >= d) ? s[t - d] : 0;
    __syncthreads();
    s[t] += x;
  }
  __syncthreads();
  if (t < nb) bsum[t] = s[t];                  // inclusive block sums
}

__global__ __launch_bounds__(256) void k_scan3(
    int* __restrict__ start, const int* __restrict__ bsum, int n) {
  int b = blockIdx.x, idx = b * 256 + threadIdx.x;
  if (idx < n) {
    int off = (b > 0) ? bsum[b - 1] : 0;
    start[idx + 1] += off;
    if (idx == 0) start[0] = 0;
  }
}

// atomic-free bucket fill: p = start[col] + rank; writes src + FINAL weight
__global__ __launch_bounds__(256) void k_fill(
    const int* __restrict__ attr, const float* __restrict__ emb,
    const int* __restrict__ row, const int* __restrict__ col,
    const int* __restrict__ rank, const int* __restrict__ start,
    const float* __restrict__ dinv, int* __restrict__ srcs,
    float* __restrict__ wts, int E) {
  int e = blockIdx.x * 256 + threadIdx.x;
  if (e < E) {
    int r = row[e], c = col[e];
    int p = start[c] + rank[e];
    srcs[p] = r;
    wts[p] = dinv[r] * emb[attr[e]] * dinv[c];
  }
}

__device__ __forceinline__ void agg_fma(float s, const float4& v, float4& acc) {
  acc.x = fmaf(s, v.x, acc.x);
  acc.y = fmaf(s, v.y, acc.y);
  acc.z = fmaf(s, v.z, acc.z);
  acc.w = fmaf(s, v.w, acc.w);
}

// out[i][:] = bias + snorm[i]*h[i][:] + sum_e wts[e]*h[srcs[e]][:]
// 32 lanes per node, float4 per lane (128 channels). 8-deep gather pipeline.
__global__ __launch_bounds__(256) void k_agg_csr(
    const float* __restrict__ h, const int* __restrict__ start,
    const int* __restrict__ srcs, const float* __restrict__ wts,
    const float* __restrict__ snorm, const float* __restrict__ bias,
    float* __restrict__ out, int n) {
  int tid = blockIdx.x * 256 + threadIdx.x;
  int i = tid >> 5;
  if (i >= n) return;
  int lane = tid & 31;
  const float4* h4 = (const float4*)h;
  float4 acc = ((const float4*)bias)[lane];
  float sn = snorm[i];
  float4 hv = h4[(size_t)i * 32 + lane];
  agg_fma(sn, hv, acc);

  int e = start[i], eend = start[i + 1];

  while (e < eend && (e & 3)) {
    float w = wts[e];
    float4 v = h4[(size_t)srcs[e] * 32 + lane];
    agg_fma(w, v, acc);
    ++e;
  }

  for (; e + 8 <= eend; e += 8) {
    int4   s0 = *(const int4*)&srcs[e];
    int4   s1 = *(const int4*)&srcs[e + 4];
    float4 w0 = *(const float4*)&wts[e];
    float4 w1 = *(const float4*)&wts[e + 4];
    float4 v0 = h4[(size_t)s0.x * 32 + lane];
    float4 v1 = h4[(size_t)s0.y * 32 + lane];
    float4 v2 = h4[(size_t)s0.z * 32 + lane];
    float4 v3 = h4[(size_t)s0.w * 32 + lane];
    float4 v4 = h4[(size_t)s1.x * 32 + lane];
    float4 v5 = h4[(size_t)s1.y * 32 + lane];
    float4 v6 = h4[(size_t)s1.z * 32 + lane];
    float4 v7 = h4[(size_t)s1.w * 32 + lane];
    agg_fma(w0.x, v0, acc); agg_fma(w0.y, v1, acc);
    agg_fma(w0.z, v2, acc); agg_fma(w0.w, v3, acc);
    agg_fma(w1.x, v4, acc); agg_fma(w1.y, v5, acc);
    agg_fma(w1.z, v6, acc); agg_fma(w1.w, v7, acc);
  }

  if (e + 4 <= eend) {
    int4   s0 = *(const int4*)&srcs[e];
    float4 w0 = *(const float4*)&wts[e];
    float4 v0 = h4[(size_t)s0.x * 32 + lane];
    float4 v1 = h4[(size_t)s0.y * 32 + lane];
    float4 v2 = h4[(size_t)s0.z * 32 + lane];
    float4 v3 = h4[(size_t)s0.w * 32 + lane];
    agg_fma(w0.x, v0, acc); agg_fma(w0.y, v1, acc);
    agg_fma(w0.z, v2, acc); agg_fma(w0.w, v3, acc);
    e += 4;
  }

  for (; e < eend; ++e) {
    float w = wts[e];
    float4 v = h4[(size_t)srcs[e] * 32 + lane];
    agg_fma(w, v, acc);
  }

  ((float4*)out)[(size_t)i * 32 + lane] = acc;
}

// GEMM: out[M x HOUT] = act( f(A[M x 128]) @ W[128 x HOUT] + bias )
// BN=64 col tiles; persistent; 2 blocks/CU; register-prefetch pipeline.
// ACT: 0 none, 1 relu, 2 sigmoid. RELU_IN: relu on A load.
// HIST: interleave packed edge histogram (atomic 1<<(10*attr); field-sum of
// old value = dense in-bucket rank) with the tile loop.
template <int HOUT, int ACT, bool RELU_IN, bool HIST>
__global__ __launch_bounds__(256, 2) void k_gemm(
    const float* __restrict__ A, const float* __restrict__ W,
    const float* __restrict__ bias, float* __restrict__ out, int M,
    const int* __restrict__ hcol, const int* __restrict__ hattr,
    int* __restrict__ hcnt, int* __restrict__ hrank, int E) {
  constexpr int NCT = HOUT / 64;   // column tiles
  constexpr int W4R = HOUT / 4;    // float4 per W row
  __shared__ float Ws[128 * 64];   // 32 KB
  __shared__ float Xs[64][132];    // 33 KB

  const int t = threadIdx.x;
  const int ct = blockIdx.x % NCT;
  const int rt0 = blockIdx.x / NCT;
  const int rstride = gridDim.x / NCT;
  const int ntiles = (M + 63) >> 6;

  for (int i = t; i < 128 * 16; i += 256) {
    int k = i >> 4, j4 = i & 15;
    ((float4*)Ws)[i] = ((const float4*)W)[k * W4R + ct * 16 + j4];
  }

  const int tc = t & 15;
  const int tr = t >> 4;
  const float4* A4 = (const float4*)A;
  const int r0 = t >> 5, c40 = t & 31;

  const int g = blockIdx.x * 256 + t;
  const int G = gridDim.x * 256;
  int jtile = 0;

  float4 pre[8];
  auto load_tile = [&](int rt) {
#pragma unroll
    for (int q = 0; q < 8; ++q) {
      int gr = (rt << 6) + r0 + q * 8;
      pre[q] = (gr < M) ? A4[(size_t)gr * 32 + c40]
                        : make_float4(0.f, 0.f, 0.f, 0.f);
    }
  };
  auto store_tile = [&]() {
#pragma unroll
    for (int q = 0; q < 8; ++q) {
      float4 v = pre[q];
      if (RELU_IN) {
        v.x = fmaxf(v.x, 0.f); v.y = fmaxf(v.y, 0.f);
        v.z = fmaxf(v.z, 0.f); v.w = fmaxf(v.w, 0.f);
      }
      *(float4*)&Xs[r0 + q * 8][c40 * 4] = v;
    }
  };

  if (rt0 < ntiles) {
    load_tile(rt0);
    __syncthreads();
    store_tile();
    __syncthreads();

    for (int rt = rt0; rt < ntiles; rt += rstride) {
      const int nxt = rt + rstride;
      if (nxt < ntiles) load_tile(nxt);

      int he0 = -1, he1 = -1, he2 = -1;
      int hr0 = 0, hr1 = 0, hr2 = 0;
      if (HIST) {
        int base = (jtile * 3) * G + g;
        if (base < E) {
          he0 = base;
          hr0 = atomicAdd(&hcnt[hcol[he0]], 1 << (10 * hattr[he0]));
        }
        if (base + G < E) {
          he1 = base + G;
          hr1 = atomicAdd(&hcnt[hcol[he1]], 1 << (10 * hattr[he1]));
        }
        if (base + 2 * G < E) {
          he2 = base + 2 * G;
          hr2 = atomicAdd(&hcnt[hcol[he2]], 1 << (10 * hattr[he2]));
        }
      }

      const int m0 = rt << 6;
      float acc[4][4];
#pragma unroll
      for (int rr = 0; rr < 4; ++rr)
        acc[rr][0] = acc[rr][1] = acc[rr][2] = acc[rr][3] = 0.f;

#pragma unroll 4
      for (int k4 = 0; k4 < 32; ++k4) {
        float4 wv[4], av[4];
#pragma unroll
        for (int kk = 0; kk < 4; ++kk)
          wv[kk] = ((const float4*)Ws)[(k4 * 4 + kk) * 16 + tc];
#pragma unroll
        for (int rr = 0; rr < 4; ++rr)
          av[rr] = *(const float4*)&Xs[tr * 4 + rr][k4 * 4];
#pragma unroll
        for (int rr = 0; rr < 4; ++rr) {
          acc[rr][0] = fmaf(av[rr].x, wv[0].x, acc[rr][0]);
          acc[rr][1] = fmaf(av[rr].x, wv[0].y, acc[rr][1]);
          acc[rr][2] = fmaf(av[rr].x, wv[0].z, acc[rr][2]);
          acc[rr][3] = fmaf(av[rr].x, wv[0].w, acc[rr][3]);
          acc[rr][0] = fmaf(av[rr].y, wv[1].x, acc[rr][0]);
          acc[rr][1] = fmaf(av[rr].y, wv[1].y, acc[rr][1]);
          acc[rr][2] = fmaf(av[rr].y, wv[1].z, acc[rr][2]);
          acc[rr][3] = fmaf(av[rr].y, wv[1].w, acc[rr][3]);
          acc[rr][0] = fmaf(av[rr].z, wv[2].x, acc[rr][0]);
          acc[rr][1] = fmaf(av[rr].z, wv[2].y, acc[rr][1]);
          acc[rr][2] = fmaf(av[rr].z, wv[2].z, acc[rr][2]);
          acc[rr][3] = fmaf(av[rr].z, wv[2].w, acc[rr][3]);
          acc[rr][0] = fmaf(av[rr].w, wv[3].x, acc[rr][0]);
          acc[rr][1] = fmaf(av[rr].w, wv[3].y, acc[rr][1]);
          acc[rr][2] = fmaf(av[rr].w, wv[3].z, acc[rr][2]);
          acc[rr][3] = fmaf(av[rr].w, wv[3].w, acc[rr][3]);
        }
      }

#pragma unroll
      for (int rr = 0; rr < 4; ++rr) {
        int gr = m0 + tr * 4 + rr;
        if (gr >= M) continue;
        float4 v = make_float4(acc[rr][0], acc[rr][1], acc[rr][2], acc[rr][3]);
        if (bias) {
          const float4 bv = *(const float4*)&bias[ct * 64 + tc * 4];
          v.x += bv.x; v.y += bv.y; v.z += bv.z; v.w += bv.w;
        }
        if (ACT == 1) {
          v.x = fmaxf(v.x, 0.f); v.y = fmaxf(v.y, 0.f);
          v.z = fmaxf(v.z, 0.f); v.w = fmaxf(v.w, 0.f);
        } else if (ACT == 2) {
          v.x = 1.f / (1.f + __expf(-v.x));
          v.y = 1.f / (1.f + __expf(-v.y));
          v.z = 1.f / (1.f + __expf(-v.z));
          v.w = 1.f / (1.f + __expf(-v.w));
        }
        ((float4*)out)[(size_t)gr * W4R + ct * 16 + tc] = v;
      }

      if (HIST) {
        // atomic returns consumed here; field-sum = dense in-bucket rank
        if (he0 >= 0)
          hrank[he0] = (hr0 & 1023) + ((hr0 >> 10) & 1023) + ((hr0 >> 20) & 1023);
        if (he1 >= 0)
          hrank[he1] = (hr1 & 1023) + ((hr1 >> 10) & 1023) + ((hr1 >> 20) & 1023);
        if (he2 >= 0)
          hrank[he2] = (hr2 & 1023) + ((hr2 >> 10) & 1023) + ((hr2 >> 20) & 1023);
        ++jtile;
      }

      if (nxt < ntiles) {
        __syncthreads();
        store_tile();
        __syncthreads();
      }
    }
  }

  if (HIST) {
    for (long long m = 3LL * jtile;; ++m) {
      long long e = m * G + g;
      if (e >= E) break;
      int a = hattr[e];
      int old = atomicAdd(&hcnt[hcol[e]], 1 << (10 * a));
      hrank[e] = (old & 1023) + ((old >> 10) & 1023) + ((old >> 20) & 1023);
    }
  }
}

extern "C" void kernel_launch(void* const* d_in, const int* in_sizes, int n_in,
                              void* d_out, int out_size, void* d_ws, size_t ws_size,
                              hipStream_t stream) {
  const float* x        = (const float*)d_in[0];
  const float* edge_emb = (const float*)d_in[1];
  const float* W1 = (const float*)d_in[2];  const float* b1 = (const float*)d_in[3];
  const float* W2 = (const float*)d_in[4];  const float* b2 = (const float*)d_in[5];
  const float* W3 = (const float*)d_in[6];  const float* b3 = (const float*)d_in[7];
  const float* cW1 = (const float*)d_in[8]; const float* cb1 = (const float*)d_in[9];
  const float* cW2 = (const float*)d_in[10]; const float* cb2 = (const float*)d_in[11];
  const int* eidx  = (const int*)d_in[12];
  const int* eattr = (const int*)d_in[13];

  const int N = in_sizes[0] / 128;
  const int E = in_sizes[13];
  const int* row = eidx;        // edge_index[0] = source
  const int* col = eidx + E;    // edge_index[1] = target

  float* out = (float*)d_out;

  // workspace layout, 16B-aligned slots (element counts rounded to x4)
  size_t off = 0;
  auto alloc4 = [&](size_t n) { size_t o = off; off += (n + 3) & ~(size_t)3; return o; };
  float* wsf = (float*)d_ws;
  int*   wsi = (int*)d_ws;

  float* dinv   = wsf + alloc4(N);
  float* snorm  = wsf + alloc4(N);
  int*   cnt    = wsi + alloc4(N);       // packed 3x10-bit per-attr counts
  int*   start  = wsi + alloc4(N + 1);
  int*   bsum   = wsi + alloc4(256);
  int*   rank   = wsi + alloc4(E);
  int*   srcs   = wsi + alloc4(E);
  float* wts    = wsf + alloc4(E);       // final normalized weights
  float* bufA   = wsf + alloc4((size_t)N * 128);
  float* bufB   = wsf + alloc4((size_t)N * 128);

  const int gN  = (N + 255) / 256;
  const int gE  = (E + 255) / 256;
  const int gA  = (N * 32 + 255) / 256;
  const int nb  = gN;  // scan blocks
  const int gGemm = 512;   // persistent: 2 blocks/CU

  // cnt must be zero before the interleaved hist in the layer-1 GEMM
  (void)hipMemsetAsync(cnt, 0, (size_t)N * sizeof(int), stream);

  // ---- layer-1 GEMM with interleaved packed edge histogram ----
  k_gemm<128, 0, false, true><<<gGemm, 256, 0, stream>>>(
      x, W1, nullptr, bufA, N, col, eattr, cnt, rank, E);

  // ---- CSR build: scan (+deg/dinv/snorm inline) -> fill (normalized) ----
  k_scan1<<<nb, 256, 0, stream>>>(cnt, start, bsum, edge_emb, dinv, snorm, N);
  k_scan2<<<1, 256, 0, stream>>>(bsum, nb);
  k_scan3<<<nb, 256, 0, stream>>>(start, bsum, N);
  k_fill<<<gE, 256, 0, stream>>>(eattr, edge_emb, row, col, rank, start,
                                 dinv, srcs, wts, E);

  // ---- layer 1 agg ----
  k_agg_csr<<<gA, 256, 0, stream>>>(bufA, start, srcs, wts, snorm, b1, bufB, N);
  // ---- layer 2 ----
  k_gemm<128, 0, true, false><<<gGemm, 256, 0, stream>>>(
      bufB, W2, nullptr, bufA, N, nullptr, nullptr, nullptr, nullptr, 0);
  k_agg_csr<<<gA, 256, 0, stream>>>(bufA, start, srcs, wts, snorm, b2, bufB, N);
  // ---- layer 3 ----
  k_gemm<128, 0, true, false><<<gGemm, 256, 0, stream>>>(
      bufB, W3, nullptr, bufA, N, nullptr, nullptr, nullptr, nullptr, 0);
  k_agg_csr<<<gA, 256, 0, stream>>>(bufA, start, srcs, wts, snorm, b3, bufB, N);

  // ---- classifier (two plain GEMMs, 2 blocks/CU each) ----
  k_gemm<128, 1, true, false><<<gGemm, 256, 0, stream>>>(
      bufB, cW1, cb1, bufA, N, nullptr, nullptr, nullptr, nullptr, 0);
  k_gemm<64, 2, false, false><<<gGemm, 256, 0, stream>>>(
      bufA, cW2, cb2, out, N, nullptr, nullptr, nullptr, nullptr, 0);
}